// Round 15
// baseline (50.077 us; speedup 1.0000x reference)
//
#include <hip/hip_runtime.h>

typedef __bf16 bf16x8 __attribute__((ext_vector_type(8)));
typedef float f32x16 __attribute__((ext_vector_type(16)));
typedef unsigned u32x2 __attribute__((ext_vector_type(2)));

#define BB 2
#define HH 56
#define WW 56
#define NN 2
#define CC 128
#define NH 8
#define DD 16
#define WSP 7
#define LQ 784           // tokens per window = 56*7*2
#define KB_TOK 800       // K rows (zero-padded 784..799)
#define VT_STRIDE 808    // V^T token stride (bf16 elems)
#define NKC 25           // K chunks of 32
#define NINST 128        // 16 windows * 8 heads
#define BPI 5            // blocks per instance
#define NTHR 640         // 10 waves: 5 Q-tiles x 2 K-halves

// LDS layout (bytes): K [800][16] bf16 (swizzled 16B units) | V^T [16][808]
// bf16 | w [9][16] f32 | ones | red [5][64][10] f32
#define K_OFF 0
#define V_OFF 25600
#define W_OFF 51456
#define ONES_OFF 52032
#define RED_OFF 52064
#define SMEM_BYTES 64864   // -> 2 blocks/CU, 20 waves/CU

// scale * log2(e) so P = exp2(S) directly (no max-tracking; S bounded)
#define QSCALE 0.3606737602222409f

union U2 { __bf16 h[2]; unsigned u; };
union U4 { unsigned u[4]; bf16x8 v; };
union H8 { bf16x8 v; uint4 q; };

static __device__ __forceinline__ float4 f4zero() { float4 r; r.x = r.y = r.z = r.w = 0.f; return r; }
static __device__ __forceinline__ float4 f4add(float4 a, float4 b) {
    float4 r; r.x = a.x + b.x; r.y = a.y + b.y; r.z = a.z + b.z; r.w = a.w + b.w; return r;
}
static __device__ __forceinline__ float4 f4fma(float4 acc, float4 w, float4 s) {
    acc.x += w.x * s.x; acc.y += w.y * s.y; acc.z += w.z * s.z; acc.w += w.w * s.w; return acc;
}

// R11/R14 pipeline, 10-wave K-split blocks (de-confounded R13): pack K/V to
// LDS once per block -> wave (tile, khalf) runs chunks c = khalf, khalf+2,...
// -> halves combine in LDS -> khalf-0 wave does RPE conv + store (no RMW).
// Grid 640 = 128 inst * 5 parts, XCD-affine.
__global__ __launch_bounds__(NTHR) void attn_fused(const float* __restrict__ q_g,
                                                   const float* __restrict__ k_g,
                                                   const float* __restrict__ v_g,
                                                   const float* __restrict__ conv_w,
                                                   float* __restrict__ out) {
    __shared__ alignas(16) char smem[SMEM_BYTES];
    uint4*  K16   = (uint4*)(smem + K_OFF);      // 16B units, swizzled
    __bf16* Vlds  = (__bf16*)(smem + V_OFF);
    float*  wlds  = (float*)(smem + W_OFF);
    __bf16* onesb = (__bf16*)(smem + ONES_OFF);
    float*  red   = (float*)(smem + RED_OFF);    // [5][64][10]

    const int bid  = blockIdx.x;
    const int g    = bid >> 3;             // 0..79
    const int inst = (bid & 7) + 8 * (g / BPI);
    const int part = g % BPI;
    const int head = inst & 7;
    const int win  = inst >> 3;
    const int b    = win >> 3, wj = win & 7;
    const int tid  = threadIdx.x;

    // ---- stage conv weights transposed [k][16] + ones buffer ----
    if (tid < 144) {
        int c = tid & 15, k = tid >> 4;
        wlds[k * 16 + c] = conv_w[(head * 16 + c) * 9 + k];
    } else if (tid < 160) {
        onesb[tid - 144] = (__bf16)1.f;
    }

    // ---- pack phase: f32 K/V -> bf16 LDS (K swizzled, V^T transposed) ----
    for (int tok = tid; tok < KB_TOK; tok += NTHR) {
        if (tok < LQ) {
            int tpos = tok >> 1, tn = tok & 1;
            int ty = tpos / WSP, txl = tpos - ty * WSP;
            long off = ((long)(((b * HH + ty) * WW + wj * WSP + txl) * NN + tn)) * CC + head * DD;

            float kv[16], vv[16];
            *(float4*)&kv[0]  = *(const float4*)(k_g + off);
            *(float4*)&kv[4]  = *(const float4*)(k_g + off + 4);
            *(float4*)&kv[8]  = *(const float4*)(k_g + off + 8);
            *(float4*)&kv[12] = *(const float4*)(k_g + off + 12);
            *(float4*)&vv[0]  = *(const float4*)(v_g + off);
            *(float4*)&vv[4]  = *(const float4*)(v_g + off + 4);
            *(float4*)&vv[8]  = *(const float4*)(v_g + off + 8);
            *(float4*)&vv[12] = *(const float4*)(v_g + off + 12);

            H8 lo, hi;
#pragma unroll
            for (int i = 0; i < 8; ++i) { lo.v[i] = (__bf16)kv[i]; hi.v[i] = (__bf16)kv[8 + i]; }
            int sw = tok & 7;
            K16[(tok * 2)     ^ sw] = lo.q;
            K16[(tok * 2 + 1) ^ sw] = hi.q;
#pragma unroll
            for (int d = 0; d < 16; ++d)
                Vlds[d * VT_STRIDE + tok] = (__bf16)vv[d];
        } else {
            H8 z; z.q = make_uint4(0, 0, 0, 0);
            int sw = tok & 7;
            K16[(tok * 2)     ^ sw] = z.q;
            K16[(tok * 2 + 1) ^ sw] = z.q;
#pragma unroll
            for (int d = 0; d < 16; ++d)
                Vlds[d * VT_STRIDE + tok] = (__bf16)0.f;
        }
    }
    __syncthreads();

    // ---- per-wave geometry ----
    const int w     = tid >> 6;            // 0..9
    const int lane  = tid & 63;
    const int col   = lane & 31;           // query col / key row / V^T row
    const int h     = lane >> 5;
    const int tile  = w >> 1;              // 0..4
    const int khalf = w & 1;               // 0 or 1
    const int qt    = part * BPI + tile;   // 0..24
    const int myq   = qt * 32 + col;
    const int sib   = myq ^ 1;

    const int myqc = myq < LQ ? myq : LQ - 1;
    const int pos = myqc >> 1, n = myqc & 1;
    const int y = pos / WSP, xl = pos - y * WSP;
    const long ooff = ((long)(((b * HH + y) * WW + wj * WSP + xl) * NN + n)) * CC + head * DD;

    // Q fragment (B operand): col=query, k = d = 8h..8h+7; scale*log2e folded
    bf16x8 qfv;
    {
        const float* qp = q_g + ooff + 8 * h;
        float qv[8];
        *(float4*)&qv[0] = *(const float4*)qp;
        *(float4*)&qv[4] = *(const float4*)(qp + 4);
        H8 qq;
#pragma unroll
        for (int i = 0; i < 8; ++i) qq.v[i] = (__bf16)(qv[i] * QSCALE);
        qfv = qq.v;
    }

    f32x16 acc, zv;
#pragma unroll
    for (int i = 0; i < 16; ++i) { acc[i] = 0.f; zv[i] = 0.f; }

    // swizzled K read base: tok = c*32+col -> idx16 = c*64 + col*2 + h; the
    // XOR folds into a constant lane base since (c*64)&7 == 0.
    const uint4* kbase = K16 + ((col * 2 + h) ^ (col & 7));   // + c*64
    const char* vbase;
    int vstep, tstep;
    if (col < 16) {
        vbase = (const char*)Vlds + col * (VT_STRIDE * 2) + h * 16;
        vstep = 64; tstep = 32;
    } else {
        vbase = (const char*)onesb;        // stride-0 ones broadcast (lsum)
        vstep = 0; tstep = 0;
    }

    for (int c = khalf; c < NKC; c += 2) {
        U4 kf;
        *(uint4*)&kf = kbase[c * 64];
        f32x16 st = __builtin_amdgcn_mfma_f32_32x32x16_bf16(kf.v, qfv, zv, 0, 0, 0);

        float p[16];
        if (c == qt || c == NKC - 1) {
#pragma unroll
            for (int r = 0; r < 16; ++r) {
                int kr = (r & 3) + 8 * (r >> 2) + 4 * h;
                int gk = c * 32 + kr;
                p[r] = (gk >= LQ || gk == sib) ? 0.f : __builtin_amdgcn_exp2f(st[r]);
            }
        } else {
#pragma unroll
            for (int r = 0; r < 16; ++r) p[r] = __builtin_amdgcn_exp2f(st[r]);
        }

        unsigned pk[4][2];
#pragma unroll
        for (int b2 = 0; b2 < 4; ++b2) {
            U2 a, bb;
            a.h[0]  = (__bf16)p[4 * b2 + 0];
            a.h[1]  = (__bf16)p[4 * b2 + 1];
            bb.h[0] = (__bf16)p[4 * b2 + 2];
            bb.h[1] = (__bf16)p[4 * b2 + 3];
            pk[b2][0] = a.u;
            pk[b2][1] = bb.u;
        }

#pragma unroll
        for (int t = 0; t < 2; ++t) {
            U4 pb;
#pragma unroll
            for (int j = 0; j < 2; ++j) {
#if __has_builtin(__builtin_amdgcn_permlane32_swap)
                u32x2 rr = __builtin_amdgcn_permlane32_swap(pk[2 * t][j], pk[2 * t + 1][j], false, false);
                pb.u[j]     = rr[0];
                pb.u[2 + j] = rr[1];
#else
                unsigned swa = __shfl_xor(pk[2 * t][j], 32, 64);
                unsigned swb = __shfl_xor(pk[2 * t + 1][j], 32, 64);
                pb.u[j]     = h ? swb : pk[2 * t][j];
                pb.u[2 + j] = h ? pk[2 * t + 1][j] : swa;
#endif
            }
            bf16x8 vf = *(const bf16x8*)(vbase + c * vstep + t * tstep);
            acc = __builtin_amdgcn_mfma_f32_32x32x16_bf16(vf, pb.v, acc, 0, 0, 0);
        }
    }

    // ---- combine the two K-halves via LDS ----
    if (khalf) {
        float* rp = red + (tile * 64 + lane) * 10;
#pragma unroll
        for (int i = 0; i < 9; ++i) rp[i] = acc[i];
    }
    __syncthreads();

    if (!khalf && myq < LQ) {
        const float* rp = red + (tile * 64 + lane) * 10;
        float o[9];
#pragma unroll
        for (int i = 0; i < 9; ++i) o[i] = acc[i] + rp[i];
        float inv = 1.f / o[8];            // lsum (ones broadcast row)

        // ---- in-register depthwise-conv RPE + write out (no RMW) ----
        const int xg = wj * WSP + xl;
        const long rowbase = ((long)(b * HH + y) * WW + xg) * (NN * CC) + head * DD;

        float4 cv0 = f4zero(), cv1 = f4zero();
        float4 sc0 = f4zero(), sc1 = f4zero();
        float4 vn0 = f4zero(), vn1 = f4zero();

#pragma unroll
        for (int dy = -1; dy <= 1; ++dy) {
            int yy = y + dy;
#pragma unroll
            for (int dx = -1; dx <= 1; ++dx) {
                int xx = xg + dx;
                if (yy < 0 || yy >= HH || xx < 0 || xx >= WW) continue;
                int k = (dy + 1) * 3 + (dx + 1);
                const float* p = v_g + rowbase + ((long)dy * WW + dx) * (NN * CC);
                float4 a0 = *(const float4*)(p + 4 * h);
                float4 b0 = *(const float4*)(p + CC + 4 * h);
                float4 a1 = *(const float4*)(p + 8 + 4 * h);
                float4 b1 = *(const float4*)(p + CC + 8 + 4 * h);
                float4 w0 = *(const float4*)(wlds + k * 16 + 4 * h);
                float4 w1 = *(const float4*)(wlds + k * 16 + 8 + 4 * h);
                float4 S0 = f4add(a0, b0);
                float4 S1 = f4add(a1, b1);
                cv0 = f4fma(cv0, w0, S0);
                cv1 = f4fma(cv1, w1, S1);
                if (dy == 0 && dx == 0) {
                    sc0 = S0; sc1 = S1;
                    vn0 = n ? b0 : a0;
                    vn1 = n ? b1 : a1;
                }
            }
        }
        float4 wc0 = *(const float4*)(wlds + 4 * 16 + 4 * h);
        float4 wc1 = *(const float4*)(wlds + 4 * 16 + 8 + 4 * h);

        float* po = out + ooff;
        float4 r0, r1;
        r0.x = cv0.x + wc0.x * (vn0.x - sc0.x) + o[0] * inv;
        r0.y = cv0.y + wc0.y * (vn0.y - sc0.y) + o[1] * inv;
        r0.z = cv0.z + wc0.z * (vn0.z - sc0.z) + o[2] * inv;
        r0.w = cv0.w + wc0.w * (vn0.w - sc0.w) + o[3] * inv;
        r1.x = cv1.x + wc1.x * (vn1.x - sc1.x) + o[4] * inv;
        r1.y = cv1.y + wc1.y * (vn1.y - sc1.y) + o[5] * inv;
        r1.z = cv1.z + wc1.z * (vn1.z - sc1.z) + o[6] * inv;
        r1.w = cv1.w + wc1.w * (vn1.w - sc1.w) + o[7] * inv;
        *(float4*)(po + 4 * h) = r0;
        *(float4*)(po + 8 + 4 * h) = r1;
    }
}

extern "C" void kernel_launch(void* const* d_in, const int* in_sizes, int n_in,
                              void* d_out, int out_size, void* d_ws, size_t ws_size,
                              hipStream_t stream) {
    const float* q = (const float*)d_in[0];
    const float* k = (const float*)d_in[1];
    const float* v = (const float*)d_in[2];
    const float* w = (const float*)d_in[3];
    float* out = (float*)d_out;

    attn_fused<<<NINST * BPI, NTHR, 0, stream>>>(q, k, v, w, out);
}

// Round 16
// 39.970 us; speedup vs baseline: 1.2529x; 1.2529x over previous
//
#include <hip/hip_runtime.h>

typedef __bf16 bf16x8 __attribute__((ext_vector_type(8)));
typedef float f32x16 __attribute__((ext_vector_type(16)));
typedef unsigned u32x2 __attribute__((ext_vector_type(2)));

#define BB 2
#define HH 56
#define WW 56
#define NN 2
#define CC 128
#define NH 8
#define DD 16
#define WSP 7
#define LQ 784           // tokens per window = 56*7*2
#define KB_TOK 800       // K rows (zero-padded 784..799)
#define VT_STRIDE 808    // V^T token stride (bf16 elems)
#define NKC 25           // K chunks of 32
#define NINST 128        // 16 windows * 8 heads
#define BPI 5            // blocks per instance
#define NWAVE 5          // waves per block (1 Q-tile each)
#define KW_UNITS 1600    // uint4 units per instance in packed-K ws (800 tok * 2)

// LDS layout (bytes): V^T [16][808] bf16 | w [9][16] f32 | ones
#define V_OFF 0
#define W_OFF 25856
#define ONES_OFF 26432
#define SMEM_BYTES 26464   // 6 blocks/CU by LDS (158.8KB); 6 by wave cap -> 30 waves/CU

// scale * log2(e) so P = exp2(S) directly (no max-tracking; S bounded)
#define QSCALE 0.3606737602222409f

union U2 { __bf16 h[2]; unsigned u; };
union U4 { unsigned u[4]; bf16x8 v; };
union H8 { bf16x8 v; uint4 q; };

static __device__ __forceinline__ float4 f4zero() { float4 r; r.x = r.y = r.z = r.w = 0.f; return r; }
static __device__ __forceinline__ float4 f4add(float4 a, float4 b) {
    float4 r; r.x = a.x + b.x; r.y = a.y + b.y; r.z = a.z + b.z; r.w = a.w + b.w; return r;
}
static __device__ __forceinline__ float4 f4fma(float4 acc, float4 w, float4 s) {
    acc.x += w.x * s.x; acc.y += w.y * s.y; acc.z += w.z * s.z; acc.w += w.w * s.w; return acc;
}

// ---------------- Kernel 1: pack K fragments to ws (fragment-linear) -------
// ws[inst*1600 + tok*2 + half] = 16B unit holding bf16 K[tok][8*half..8*half+7].
// One thread per token; reads coalesced f32, writes 32B/thread consecutive.
__global__ __launch_bounds__(256) void pack_k(const float* __restrict__ k_g,
                                              uint4* __restrict__ kws) {
    int idx = blockIdx.x * blockDim.x + threadIdx.x;   // over NINST*KB_TOK
    if (idx >= NINST * KB_TOK) return;
    int inst = idx / KB_TOK;
    int tok  = idx - inst * KB_TOK;
    uint4* dst = kws + (long)inst * KW_UNITS + tok * 2;

    if (tok >= LQ) {
        uint4 z = make_uint4(0, 0, 0, 0);
        dst[0] = z; dst[1] = z;
        return;
    }
    int head = inst & 7, win = inst >> 3;
    int b = win >> 3, wj = win & 7;
    int pos = tok >> 1, n = tok & 1;
    int y = pos / WSP, xl = pos - y * WSP;
    long off = ((long)(((b * HH + y) * WW + wj * WSP + xl) * NN + n)) * CC + head * DD;

    float kv[16];
    *(float4*)&kv[0]  = *(const float4*)(k_g + off);
    *(float4*)&kv[4]  = *(const float4*)(k_g + off + 4);
    *(float4*)&kv[8]  = *(const float4*)(k_g + off + 8);
    *(float4*)&kv[12] = *(const float4*)(k_g + off + 12);
    H8 lo, hi;
#pragma unroll
    for (int i = 0; i < 8; ++i) { lo.v[i] = (__bf16)kv[i]; hi.v[i] = (__bf16)kv[8 + i]; }
    dst[0] = lo.q;
    dst[1] = hi.q;
}

// ---------------- Kernel 2: attention, V^T in LDS, K from packed ws --------
// R11 pipeline with K evicted from LDS: per chunk, the wave reads 1KB of
// packed K fragments fully coalesced from the XCD-L2-resident ws. LDS holds
// only V^T (26.5KB) -> 6 blocks/CU = 30 waves/CU residency.
// Grid 640 = 128 inst * 5 parts, XCD-affine (inst&7 == bid&7).
__global__ __launch_bounds__(320) void attn_fused(const float* __restrict__ q_g,
                                                  const uint4* __restrict__ kws,
                                                  const float* __restrict__ v_g,
                                                  const float* __restrict__ conv_w,
                                                  float* __restrict__ out) {
    __shared__ alignas(16) char smem[SMEM_BYTES];
    __bf16* Vlds  = (__bf16*)(smem + V_OFF);
    float*  wlds  = (float*)(smem + W_OFF);
    __bf16* onesb = (__bf16*)(smem + ONES_OFF);

    const int bid  = blockIdx.x;
    const int g    = bid >> 3;             // 0..79
    const int inst = (bid & 7) + 8 * (g / BPI);
    const int part = g % BPI;
    const int head = inst & 7;
    const int win  = inst >> 3;
    const int b    = win >> 3, wj = win & 7;
    const int tid  = threadIdx.x;

    // ---- stage conv weights transposed [k][16] + ones buffer ----
    if (tid < 144) {
        int c = tid & 15, k = tid >> 4;
        wlds[k * 16 + c] = conv_w[(head * 16 + c) * 9 + k];
    } else if (tid < 160) {
        onesb[tid - 144] = (__bf16)1.f;
    }

    // ---- pack phase: f32 V -> bf16 V^T LDS ----
    for (int tok = tid; tok < KB_TOK; tok += 320) {
        if (tok < LQ) {
            int tpos = tok >> 1, tn = tok & 1;
            int ty = tpos / WSP, txl = tpos - ty * WSP;
            long off = ((long)(((b * HH + ty) * WW + wj * WSP + txl) * NN + tn)) * CC + head * DD;
            float vv[16];
            *(float4*)&vv[0]  = *(const float4*)(v_g + off);
            *(float4*)&vv[4]  = *(const float4*)(v_g + off + 4);
            *(float4*)&vv[8]  = *(const float4*)(v_g + off + 8);
            *(float4*)&vv[12] = *(const float4*)(v_g + off + 12);
#pragma unroll
            for (int d = 0; d < 16; ++d)
                Vlds[d * VT_STRIDE + tok] = (__bf16)vv[d];
        } else {
#pragma unroll
            for (int d = 0; d < 16; ++d)
                Vlds[d * VT_STRIDE + tok] = (__bf16)0.f;
        }
    }
    __syncthreads();

    // ---- per-wave geometry ----
    const int w    = tid >> 6;             // 0..4
    const int lane = tid & 63;
    const int col  = lane & 31;            // query col / key row / V^T row
    const int h    = lane >> 5;
    const int qt   = part * NWAVE + w;     // 0..24
    const int myq  = qt * 32 + col;
    const int sib  = myq ^ 1;

    const int myqc = myq < LQ ? myq : LQ - 1;
    const int pos = myqc >> 1, n = myqc & 1;
    const int y = pos / WSP, xl = pos - y * WSP;
    const long ooff = ((long)(((b * HH + y) * WW + wj * WSP + xl) * NN + n)) * CC + head * DD;

    // Q fragment (B operand): col=query, k = d = 8h..8h+7; scale*log2e folded
    bf16x8 qfv;
    {
        const float* qp = q_g + ooff + 8 * h;
        float qv[8];
        *(float4*)&qv[0] = *(const float4*)qp;
        *(float4*)&qv[4] = *(const float4*)(qp + 4);
        H8 qq;
#pragma unroll
        for (int i = 0; i < 8; ++i) qq.v[i] = (__bf16)(qv[i] * QSCALE);
        qfv = qq.v;
    }

    f32x16 acc, zv;
#pragma unroll
    for (int i = 0; i < 16; ++i) { acc[i] = 0.f; zv[i] = 0.f; }

    // K fragment source: coalesced 16B/lane from packed ws (+ c*64 per chunk)
    const uint4* kbase = kws + (long)inst * KW_UNITS + (col * 2 + h);
    const char* vbase;
    int vstep, tstep;
    if (col < 16) {
        vbase = (const char*)Vlds + col * (VT_STRIDE * 2) + h * 16;
        vstep = 64; tstep = 32;
    } else {
        vbase = (const char*)onesb;        // stride-0 ones broadcast (lsum)
        vstep = 0; tstep = 0;
    }

    for (int c = 0; c < NKC; ++c) {
        U4 kf;
        *(uint4*)&kf = kbase[c * 64];
        f32x16 st = __builtin_amdgcn_mfma_f32_32x32x16_bf16(kf.v, qfv, zv, 0, 0, 0);

        float p[16];
        if (c == qt || c == NKC - 1) {     // only these chunks need masking
#pragma unroll
            for (int r = 0; r < 16; ++r) {
                int kr = (r & 3) + 8 * (r >> 2) + 4 * h;
                int gk = c * 32 + kr;
                p[r] = (gk >= LQ || gk == sib) ? 0.f : __builtin_amdgcn_exp2f(st[r]);
            }
        } else {
#pragma unroll
            for (int r = 0; r < 16; ++r) p[r] = __builtin_amdgcn_exp2f(st[r]);
        }

        unsigned pk[4][2];
#pragma unroll
        for (int b2 = 0; b2 < 4; ++b2) {
            U2 a, bb;
            a.h[0]  = (__bf16)p[4 * b2 + 0];
            a.h[1]  = (__bf16)p[4 * b2 + 1];
            bb.h[0] = (__bf16)p[4 * b2 + 2];
            bb.h[1] = (__bf16)p[4 * b2 + 3];
            pk[b2][0] = a.u;
            pk[b2][1] = bb.u;
        }

#pragma unroll
        for (int t = 0; t < 2; ++t) {
            U4 pb;
#pragma unroll
            for (int j = 0; j < 2; ++j) {
#if __has_builtin(__builtin_amdgcn_permlane32_swap)
                u32x2 rr = __builtin_amdgcn_permlane32_swap(pk[2 * t][j], pk[2 * t + 1][j], false, false);
                pb.u[j]     = rr[0];
                pb.u[2 + j] = rr[1];
#else
                unsigned swa = __shfl_xor(pk[2 * t][j], 32, 64);
                unsigned swb = __shfl_xor(pk[2 * t + 1][j], 32, 64);
                pb.u[j]     = h ? swb : pk[2 * t][j];
                pb.u[2 + j] = h ? pk[2 * t + 1][j] : swa;
#endif
            }
            bf16x8 vf = *(const bf16x8*)(vbase + c * vstep + t * tstep);
            acc = __builtin_amdgcn_mfma_f32_32x32x16_bf16(vf, pb.v, acc, 0, 0, 0);
        }
    }

    // ---- epilogue: in-register depthwise-conv RPE + store (no RMW) ----
    // acc[8] = lsum (ones broadcast); regs 0..3 -> d=4h+r, 4..7 -> d=8+4h+(r-4)
    if (myq < LQ) {
        float inv = 1.f / acc[8];

        const int xg = wj * WSP + xl;
        const long rowbase = ((long)(b * HH + y) * WW + xg) * (NN * CC) + head * DD;

        float4 cv0 = f4zero(), cv1 = f4zero();
        float4 sc0 = f4zero(), sc1 = f4zero();
        float4 vn0 = f4zero(), vn1 = f4zero();

#pragma unroll
        for (int dy = -1; dy <= 1; ++dy) {
            int yy = y + dy;
#pragma unroll
            for (int dx = -1; dx <= 1; ++dx) {
                int xx = xg + dx;
                if (yy < 0 || yy >= HH || xx < 0 || xx >= WW) continue;
                int k = (dy + 1) * 3 + (dx + 1);
                const float* p = v_g + rowbase + ((long)dy * WW + dx) * (NN * CC);
                float4 a0 = *(const float4*)(p + 4 * h);
                float4 b0 = *(const float4*)(p + CC + 4 * h);
                float4 a1 = *(const float4*)(p + 8 + 4 * h);
                float4 b1 = *(const float4*)(p + CC + 8 + 4 * h);
                float4 w0 = *(const float4*)(wlds + k * 16 + 4 * h);
                float4 w1 = *(const float4*)(wlds + k * 16 + 8 + 4 * h);
                float4 S0 = f4add(a0, b0);
                float4 S1 = f4add(a1, b1);
                cv0 = f4fma(cv0, w0, S0);
                cv1 = f4fma(cv1, w1, S1);
                if (dy == 0 && dx == 0) {
                    sc0 = S0; sc1 = S1;
                    vn0 = n ? b0 : a0;
                    vn1 = n ? b1 : a1;
                }
            }
        }
        float4 wc0 = *(const float4*)(wlds + 4 * 16 + 4 * h);
        float4 wc1 = *(const float4*)(wlds + 4 * 16 + 8 + 4 * h);

        float* po = out + ooff;
        float4 r0, r1;
        r0.x = cv0.x + wc0.x * (vn0.x - sc0.x) + acc[0] * inv;
        r0.y = cv0.y + wc0.y * (vn0.y - sc0.y) + acc[1] * inv;
        r0.z = cv0.z + wc0.z * (vn0.z - sc0.z) + acc[2] * inv;
        r0.w = cv0.w + wc0.w * (vn0.w - sc0.w) + acc[3] * inv;
        r1.x = cv1.x + wc1.x * (vn1.x - sc1.x) + acc[4] * inv;
        r1.y = cv1.y + wc1.y * (vn1.y - sc1.y) + acc[5] * inv;
        r1.z = cv1.z + wc1.z * (vn1.z - sc1.z) + acc[6] * inv;
        r1.w = cv1.w + wc1.w * (vn1.w - sc1.w) + acc[7] * inv;
        *(float4*)(po + 4 * h) = r0;
        *(float4*)(po + 8 + 4 * h) = r1;
    }
}

extern "C" void kernel_launch(void* const* d_in, const int* in_sizes, int n_in,
                              void* d_out, int out_size, void* d_ws, size_t ws_size,
                              hipStream_t stream) {
    const float* q = (const float*)d_in[0];
    const float* k = (const float*)d_in[1];
    const float* v = (const float*)d_in[2];
    const float* w = (const float*)d_in[3];
    float* out = (float*)d_out;
    uint4* kws = (uint4*)d_ws;            // 128 * 1600 * 16B = 3.28 MB

    int n1 = NINST * KB_TOK;
    pack_k<<<(n1 + 255) / 256, 256, 0, stream>>>(k, kws);

    attn_fused<<<NINST * BPI, 320, 0, stream>>>(q, kws, v, w, out);
}

// Round 17
// 37.693 us; speedup vs baseline: 1.3285x; 1.0604x over previous
//
#include <hip/hip_runtime.h>

typedef __bf16 bf16x8 __attribute__((ext_vector_type(8)));
typedef float f32x16 __attribute__((ext_vector_type(16)));
typedef unsigned u32x2 __attribute__((ext_vector_type(2)));

#define BB 2
#define HH 56
#define WW 56
#define NN 2
#define CC 128
#define NH 8
#define DD 16
#define WSP 7
#define LQ 784           // tokens per window = 56*7*2
#define KB_TOK 800       // K rows (zero-padded 784..799)
#define VT_STRIDE 808    // V^T token stride (bf16 elems)
#define NKC 25           // K chunks of 32
#define NINST 128        // 16 windows * 8 heads
#define BPI 5            // blocks per instance
#define NWAVE 5          // waves per block (1 Q-tile each)

// LDS layout (bytes): K [800][16] bf16 (swizzled 16B units) | V^T [16][808]
// bf16 | w [9][16] f32 | ones
#define K_OFF 0
#define V_OFF 25600
#define W_OFF 51456
#define ONES_OFF 52032
#define SMEM_BYTES 52064

// scale * log2(e) so P = exp2(S) directly (no max-tracking; S bounded)
#define QSCALE 0.3606737602222409f

union U2 { __bf16 h[2]; unsigned u; };
union U4 { unsigned u[4]; bf16x8 v; };
union H8 { bf16x8 v; uint4 q; };

static __device__ __forceinline__ float4 f4zero() { float4 r; r.x = r.y = r.z = r.w = 0.f; return r; }
static __device__ __forceinline__ float4 f4add(float4 a, float4 b) {
    float4 r; r.x = a.x + b.x; r.y = a.y + b.y; r.z = a.z + b.z; r.w = a.w + b.w; return r;
}
static __device__ __forceinline__ float4 f4fma(float4 acc, float4 w, float4 s) {
    acc.x += w.x * s.x; acc.y += w.y * s.y; acc.z += w.z * s.z; acc.w += w.w * s.w; return acc;
}

// R14 base + chunk-pair fusion (all loads hoisted, 2x independent exp/pack
// between waits) + setprio around the PV MFMA cluster.
// Grid 640 = 128 inst * 5 parts, XCD-affine (inst&7 == bid&7).
__global__ __launch_bounds__(320) void attn_fused(const float* __restrict__ q_g,
                                                  const float* __restrict__ k_g,
                                                  const float* __restrict__ v_g,
                                                  const float* __restrict__ conv_w,
                                                  float* __restrict__ out) {
    __shared__ alignas(16) char smem[SMEM_BYTES];
    uint4*  K16   = (uint4*)(smem + K_OFF);      // 16B units, swizzled
    __bf16* Vlds  = (__bf16*)(smem + V_OFF);
    float*  wlds  = (float*)(smem + W_OFF);
    __bf16* onesb = (__bf16*)(smem + ONES_OFF);

    const int bid  = blockIdx.x;
    const int g    = bid >> 3;             // 0..79
    const int inst = (bid & 7) + 8 * (g / BPI);
    const int part = g % BPI;
    const int head = inst & 7;
    const int win  = inst >> 3;
    const int b    = win >> 3, wj = win & 7;
    const int tid  = threadIdx.x;

    // ---- stage conv weights transposed [k][16] + ones buffer ----
    if (tid < 144) {
        int c = tid & 15, k = tid >> 4;
        wlds[k * 16 + c] = conv_w[(head * 16 + c) * 9 + k];
    } else if (tid < 160) {
        onesb[tid - 144] = (__bf16)1.f;
    }

    // ---- pack phase: f32 K/V -> bf16 LDS (K swizzled, V^T transposed) ----
    for (int tok = tid; tok < KB_TOK; tok += 320) {
        if (tok < LQ) {
            int tpos = tok >> 1, tn = tok & 1;
            int ty = tpos / WSP, txl = tpos - ty * WSP;
            long off = ((long)(((b * HH + ty) * WW + wj * WSP + txl) * NN + tn)) * CC + head * DD;

            float kv[16], vv[16];
            *(float4*)&kv[0]  = *(const float4*)(k_g + off);
            *(float4*)&kv[4]  = *(const float4*)(k_g + off + 4);
            *(float4*)&kv[8]  = *(const float4*)(k_g + off + 8);
            *(float4*)&kv[12] = *(const float4*)(k_g + off + 12);
            *(float4*)&vv[0]  = *(const float4*)(v_g + off);
            *(float4*)&vv[4]  = *(const float4*)(v_g + off + 4);
            *(float4*)&vv[8]  = *(const float4*)(v_g + off + 8);
            *(float4*)&vv[12] = *(const float4*)(v_g + off + 12);

            H8 lo, hi;
#pragma unroll
            for (int i = 0; i < 8; ++i) { lo.v[i] = (__bf16)kv[i]; hi.v[i] = (__bf16)kv[8 + i]; }
            int sw = tok & 7;
            K16[(tok * 2)     ^ sw] = lo.q;
            K16[(tok * 2 + 1) ^ sw] = hi.q;
#pragma unroll
            for (int d = 0; d < 16; ++d)
                Vlds[d * VT_STRIDE + tok] = (__bf16)vv[d];
        } else {
            H8 z; z.q = make_uint4(0, 0, 0, 0);
            int sw = tok & 7;
            K16[(tok * 2)     ^ sw] = z.q;
            K16[(tok * 2 + 1) ^ sw] = z.q;
#pragma unroll
            for (int d = 0; d < 16; ++d)
                Vlds[d * VT_STRIDE + tok] = (__bf16)0.f;
        }
    }
    __syncthreads();

    // ---- per-wave geometry ----
    const int w    = tid >> 6;             // 0..4
    const int lane = tid & 63;
    const int col  = lane & 31;            // query col / key row / V^T row
    const int h    = lane >> 5;
    const int qt   = part * NWAVE + w;     // 0..24
    const int myq  = qt * 32 + col;
    const int sib  = myq ^ 1;

    const int myqc = myq < LQ ? myq : LQ - 1;
    const int pos = myqc >> 1, n = myqc & 1;
    const int y = pos / WSP, xl = pos - y * WSP;
    const long ooff = ((long)(((b * HH + y) * WW + wj * WSP + xl) * NN + n)) * CC + head * DD;

    // Q fragment (B operand): col=query, k = d = 8h..8h+7; scale*log2e folded
    bf16x8 qfv;
    {
        const float* qp = q_g + ooff + 8 * h;
        float qv[8];
        *(float4*)&qv[0] = *(const float4*)qp;
        *(float4*)&qv[4] = *(const float4*)(qp + 4);
        H8 qq;
#pragma unroll
        for (int i = 0; i < 8; ++i) qq.v[i] = (__bf16)(qv[i] * QSCALE);
        qfv = qq.v;
    }

    f32x16 acc, zv;
#pragma unroll
    for (int i = 0; i < 16; ++i) { acc[i] = 0.f; zv[i] = 0.f; }

    const uint4* kbase = K16 + ((col * 2 + h) ^ (col & 7));   // + c*64
    const char* vbase;
    int vstep, tstep;
    if (col < 16) {
        vbase = (const char*)Vlds + col * (VT_STRIDE * 2) + h * 16;
        vstep = 64; tstep = 32;
    } else {
        vbase = (const char*)onesb;        // stride-0 ones broadcast (lsum)
        vstep = 0; tstep = 0;
    }

    // exp+mask+pack for one 32-key chunk; returns pk (keys 8*b2+4h..+3)
    auto softmax_pack = [&](int c, const f32x16& st, unsigned pk[4][2]) {
        float p[16];
        if (c == qt || c == NKC - 1) {
#pragma unroll
            for (int r = 0; r < 16; ++r) {
                int kr = (r & 3) + 8 * (r >> 2) + 4 * h;
                int gk = c * 32 + kr;
                p[r] = (gk >= LQ || gk == sib) ? 0.f : __builtin_amdgcn_exp2f(st[r]);
            }
        } else {
#pragma unroll
            for (int r = 0; r < 16; ++r) p[r] = __builtin_amdgcn_exp2f(st[r]);
        }
#pragma unroll
        for (int b2 = 0; b2 < 4; ++b2) {
            U2 a, bb;
            a.h[0]  = (__bf16)p[4 * b2 + 0];
            a.h[1]  = (__bf16)p[4 * b2 + 1];
            bb.h[0] = (__bf16)p[4 * b2 + 2];
            bb.h[1] = (__bf16)p[4 * b2 + 3];
            pk[b2][0] = a.u;
            pk[b2][1] = bb.u;
        }
    };
    auto make_pb = [&](const unsigned pk[4][2], int t, U4& pb) {
#pragma unroll
        for (int j = 0; j < 2; ++j) {
#if __has_builtin(__builtin_amdgcn_permlane32_swap)
            u32x2 rr = __builtin_amdgcn_permlane32_swap(pk[2 * t][j], pk[2 * t + 1][j], false, false);
            pb.u[j]     = rr[0];
            pb.u[2 + j] = rr[1];
#else
            unsigned swa = __shfl_xor(pk[2 * t][j], 32, 64);
            unsigned swb = __shfl_xor(pk[2 * t + 1][j], 32, 64);
            pb.u[j]     = h ? swb : pk[2 * t][j];
            pb.u[2 + j] = h ? pk[2 * t + 1][j] : swa;
#endif
        }
    };

    for (int it = 0; it < 12; ++it) {      // chunk pair (c, c+1)
        const int c0 = 2 * it, c1 = 2 * it + 1;
        // hoist ALL loads for the pair off the dependency chain
        U4 kf0, kf1;
        *(uint4*)&kf0 = kbase[c0 * 64];
        *(uint4*)&kf1 = kbase[c1 * 64];
        bf16x8 vf00 = *(const bf16x8*)(vbase + c0 * vstep);
        bf16x8 vf01 = *(const bf16x8*)(vbase + c0 * vstep + tstep);
        bf16x8 vf10 = *(const bf16x8*)(vbase + c1 * vstep);
        bf16x8 vf11 = *(const bf16x8*)(vbase + c1 * vstep + tstep);

        f32x16 st0 = __builtin_amdgcn_mfma_f32_32x32x16_bf16(kf0.v, qfv, zv, 0, 0, 0);
        f32x16 st1 = __builtin_amdgcn_mfma_f32_32x32x16_bf16(kf1.v, qfv, zv, 0, 0, 0);

        unsigned pk0[4][2], pk1[4][2];
        softmax_pack(c0, st0, pk0);        // st0's exps overlap st1's MFMA
        softmax_pack(c1, st1, pk1);

        U4 pb00, pb01, pb10, pb11;
        make_pb(pk0, 0, pb00); make_pb(pk0, 1, pb01);
        make_pb(pk1, 0, pb10); make_pb(pk1, 1, pb11);

        __builtin_amdgcn_s_setprio(1);
        acc = __builtin_amdgcn_mfma_f32_32x32x16_bf16(vf00, pb00.v, acc, 0, 0, 0);
        acc = __builtin_amdgcn_mfma_f32_32x32x16_bf16(vf01, pb01.v, acc, 0, 0, 0);
        acc = __builtin_amdgcn_mfma_f32_32x32x16_bf16(vf10, pb10.v, acc, 0, 0, 0);
        acc = __builtin_amdgcn_mfma_f32_32x32x16_bf16(vf11, pb11.v, acc, 0, 0, 0);
        __builtin_amdgcn_s_setprio(0);
    }
    {   // tail chunk 24
        const int c = 24;
        U4 kf;
        *(uint4*)&kf = kbase[c * 64];
        bf16x8 vf0 = *(const bf16x8*)(vbase + c * vstep);
        bf16x8 vf1 = *(const bf16x8*)(vbase + c * vstep + tstep);
        f32x16 st = __builtin_amdgcn_mfma_f32_32x32x16_bf16(kf.v, qfv, zv, 0, 0, 0);
        unsigned pk[4][2];
        softmax_pack(c, st, pk);
        U4 pb0, pb1;
        make_pb(pk, 0, pb0); make_pb(pk, 1, pb1);
        __builtin_amdgcn_s_setprio(1);
        acc = __builtin_amdgcn_mfma_f32_32x32x16_bf16(vf0, pb0.v, acc, 0, 0, 0);
        acc = __builtin_amdgcn_mfma_f32_32x32x16_bf16(vf1, pb1.v, acc, 0, 0, 0);
        __builtin_amdgcn_s_setprio(0);
    }

    // ---- epilogue: in-register depthwise-conv RPE + store (no RMW) ----
    // acc[8] = lsum (ones row); regs 0..3 -> d=4h+r, 4..7 -> d=8+4h+(r-4)
    if (myq < LQ) {
        float inv = 1.f / acc[8];

        const int xg = wj * WSP + xl;
        const long rowbase = ((long)(b * HH + y) * WW + xg) * (NN * CC) + head * DD;

        float4 cv0 = f4zero(), cv1 = f4zero();
        float4 sc0 = f4zero(), sc1 = f4zero();
        float4 vn0 = f4zero(), vn1 = f4zero();

#pragma unroll
        for (int dy = -1; dy <= 1; ++dy) {
            int yy = y + dy;
#pragma unroll
            for (int dx = -1; dx <= 1; ++dx) {
                int xx = xg + dx;
                if (yy < 0 || yy >= HH || xx < 0 || xx >= WW) continue;
                int k = (dy + 1) * 3 + (dx + 1);
                const float* p = v_g + rowbase + ((long)dy * WW + dx) * (NN * CC);
                float4 a0 = *(const float4*)(p + 4 * h);
                float4 b0 = *(const float4*)(p + CC + 4 * h);
                float4 a1 = *(const float4*)(p + 8 + 4 * h);
                float4 b1 = *(const float4*)(p + CC + 8 + 4 * h);
                float4 w0 = *(const float4*)(wlds + k * 16 + 4 * h);
                float4 w1 = *(const float4*)(wlds + k * 16 + 8 + 4 * h);
                float4 S0 = f4add(a0, b0);
                float4 S1 = f4add(a1, b1);
                cv0 = f4fma(cv0, w0, S0);
                cv1 = f4fma(cv1, w1, S1);
                if (dy == 0 && dx == 0) {
                    sc0 = S0; sc1 = S1;
                    vn0 = n ? b0 : a0;
                    vn1 = n ? b1 : a1;
                }
            }
        }
        float4 wc0 = *(const float4*)(wlds + 4 * 16 + 4 * h);
        float4 wc1 = *(const float4*)(wlds + 4 * 16 + 8 + 4 * h);

        float* po = out + ooff;
        float4 r0, r1;
        r0.x = cv0.x + wc0.x * (vn0.x - sc0.x) + acc[0] * inv;
        r0.y = cv0.y + wc0.y * (vn0.y - sc0.y) + acc[1] * inv;
        r0.z = cv0.z + wc0.z * (vn0.z - sc0.z) + acc[2] * inv;
        r0.w = cv0.w + wc0.w * (vn0.w - sc0.w) + acc[3] * inv;
        r1.x = cv1.x + wc1.x * (vn1.x - sc1.x) + acc[4] * inv;
        r1.y = cv1.y + wc1.y * (vn1.y - sc1.y) + acc[5] * inv;
        r1.z = cv1.z + wc1.z * (vn1.z - sc1.z) + acc[6] * inv;
        r1.w = cv1.w + wc1.w * (vn1.w - sc1.w) + acc[7] * inv;
        *(float4*)(po + 4 * h) = r0;
        *(float4*)(po + 8 + 4 * h) = r1;
    }
}

extern "C" void kernel_launch(void* const* d_in, const int* in_sizes, int n_in,
                              void* d_out, int out_size, void* d_ws, size_t ws_size,
                              hipStream_t stream) {
    const float* q = (const float*)d_in[0];
    const float* k = (const float*)d_in[1];
    const float* v = (const float*)d_in[2];
    const float* w = (const float*)d_in[3];
    float* out = (float*)d_out;

    attn_fused<<<NINST * BPI, 320, 0, stream>>>(q, k, v, w, out);
}